// Round 6
// baseline (877.753 us; speedup 1.0000x reference)
//
#include <hip/hip_runtime.h>

#define S_TOK 16384   // S*N tokens
#define D_DIM 1024
#define F_DIM 4096
#define E_NUM 8

#define BM 256
#define BN 256
#define BK 64
#define MT_MAX 72     // sum_e ceil(cnt_e/256) <= 64 + 8 = 72

typedef short bf16x8 __attribute__((ext_vector_type(8)));
typedef float f32x4 __attribute__((ext_vector_type(4)));
typedef unsigned short ushort_t;

static __device__ __forceinline__ unsigned short f32_bf16(float f) {
  unsigned u = __float_as_uint(f);
  return (unsigned short)((u + 0x7FFFu + ((u >> 16) & 1u)) >> 16);
}

static __device__ __forceinline__ unsigned int pack_bf16x2(float a, float b) {
  unsigned ua = __float_as_uint(a);
  unsigned ub = __float_as_uint(b);
  unsigned lo = (ua + 0x7FFFu + ((ua >> 16) & 1u)) >> 16;
  unsigned hi = (ub + 0x7FFFu + ((ub >> 16) & 1u)) & 0xFFFF0000u;
  return lo | hi;
}

static __device__ __forceinline__ uint2 cvt_f4_bf4(const float4 v) {
  uint2 r;
  r.x = pack_bf16x2(v.x, v.y);
  r.y = pack_bf16x2(v.z, v.w);
  return r;
}

static __device__ __forceinline__ void load_lds16(const void* g, void* l) {
  __builtin_amdgcn_global_load_lds(g, l, 16, 0, 0);
}

// ---------------- zero counts ----------------
__global__ void zero_counts_kernel(int* counts) {
  if (threadIdx.x < E_NUM) counts[threadIdx.x] = 0;
}

// ---------------- fp32 -> bf16 cast of W1 and W2 in one launch ----------------
__global__ void cast2_kernel(const float* __restrict__ w1, ushort_t* __restrict__ o1,
                             const float* __restrict__ w2, ushort_t* __restrict__ o2) {
  const int half = 16384;
  const float* src = (blockIdx.x < half) ? w1 : w2;
  ushort_t* dst = (blockIdx.x < half) ? o1 : o2;
  const int b = (blockIdx.x < half) ? blockIdx.x : (blockIdx.x - half);
  const size_t base = ((size_t)b * blockDim.x + threadIdx.x) * 8;
  const float4 v0 = *(const float4*)(src + base);
  const float4 v1 = *(const float4*)(src + base + 4);
  const uint2 a = cvt_f4_bf4(v0), c = cvt_f4_bf4(v1);
  uint4 w; w.x = a.x; w.y = a.y; w.z = c.x; w.w = c.y;
  *(uint4*)(dst + base) = w;
}

// ---------------- gating (+ x cast to bf16) ----------------
__global__ void gate_kernel(const float* __restrict__ x,
                            const float* __restrict__ Wg,
                            ushort_t* __restrict__ xbf,
                            float* __restrict__ prob,
                            int* __restrict__ counts,
                            int* __restrict__ tok_list) {
  const int wv = threadIdx.x >> 6;
  const int lane = threadIdx.x & 63;
  const int t = blockIdx.x * 4 + wv;
  const float* xr = x + (size_t)t * D_DIM;
  ushort_t* xb = xbf + (size_t)t * D_DIM;

  float acc[E_NUM];
#pragma unroll
  for (int e = 0; e < E_NUM; ++e) acc[e] = 0.0f;

#pragma unroll
  for (int i = 0; i < 4; ++i) {
    const int k = i * 256 + lane * 4;
    const float4 v = *(const float4*)(xr + k);
    *(uint2*)(xb + k) = cvt_f4_bf4(v);
#pragma unroll
    for (int e = 0; e < E_NUM; ++e) {
      const float4 w = *(const float4*)(Wg + e * D_DIM + k);
      acc[e] += v.x * w.x + v.y * w.y + v.z * w.z + v.w * w.w;
    }
  }
#pragma unroll
  for (int e = 0; e < E_NUM; ++e) {
#pragma unroll
    for (int off = 32; off > 0; off >>= 1)
      acc[e] += __shfl_xor(acc[e], off, 64);
  }
  if (lane == 0) {
    float m = acc[0]; int bi = 0;
#pragma unroll
    for (int e = 1; e < E_NUM; ++e) {
      if (acc[e] > m) { m = acc[e]; bi = e; }
    }
    float s = 0.0f;
#pragma unroll
    for (int e = 0; e < E_NUM; ++e) s += expf(acc[e] - m);
    prob[t] = 1.0f / s;             // softmax prob of the argmax logit
    int p = atomicAdd(&counts[bi], 1);
    tok_list[bi * S_TOK + p] = t;
  }
}

// ---------------- tile plan: dense (expert, m0) table, BM=256 ----------------
__global__ void plan_kernel(const int* __restrict__ counts, int* __restrict__ plan) {
  if (threadIdx.x == 0) {
    int t = 0;
    for (int e = 0; e < E_NUM; ++e) {
      const int nt = (counts[e] + BM - 1) / BM;
      for (int i = 0; i < nt; ++i) {
        plan[1 + t] = e;
        plan[1 + MT_MAX + t] = i * BM;
        ++t;
      }
    }
    plan[0] = t;
  }
}

// ---------------- grouped GEMM: 256^2, BK=64, 2-phase + counted vmcnt ----------
// LDS[buf][0] = A tile [256 rows][64 el] linear+swizzled, [buf][1] = B tile.
// Swizzle: within a 128B row, 16B slot phys = log ^ (row&7); applied to the
// global SOURCE at stage time (LDS dest linear, rule #21) and to ds_read addrs.
// Pipeline (T4): prologue issues tiles 0,1 (16 loads outstanding). Each iter:
//   s_waitcnt vmcnt(8)  -> tile t landed, t+1 still in flight (never drain to 0)
//   s_barrier; ds_read + 64 MFMA on buf(t&1); s_barrier
//   issue tile t+2 into buf(t&1)  (clamped dummies near the tail keep the
//   outstanding count at 16 so vmcnt(8) always means "tile t landed")
template <int KDIM, int NDIM, int EPI>
__launch_bounds__(512, 2)
__global__ void ffn_kernel(const ushort_t* __restrict__ A,
                           const ushort_t* __restrict__ B,
                           const float* __restrict__ bias,
                           const float* __restrict__ prob,
                           const int* __restrict__ counts,
                           const int* __restrict__ tok_list,
                           const int* __restrict__ plan,
                           ushort_t* __restrict__ Hout,
                           float* __restrict__ out) {
  constexpr int NT = NDIM / BN;
  constexpr int NK = KDIM / BK;
  const int ntiles = plan[0];
  const int live = ntiles * NT;
  if (blockIdx.x >= live) return;
  // runtime-bijective XCD swizzle over the LIVE range (m204 formula)
  const int q = live >> 3, r = live & 7;
  const int xcd = blockIdx.x & 7, idx = blockIdx.x >> 3;
  const int wg = (xcd < r ? xcd * (q + 1) : r * (q + 1) + (xcd - r) * q) + idx;
  const int tile = wg / NT;            // m slow, n fast: A-panel hot per XCD
  const int n0 = (wg % NT) * BN;
  const int e = plan[1 + tile];
  const int m0 = plan[1 + MT_MAX + tile];
  const int cnt = counts[e];

  __shared__ ushort_t Lds[2][2][BM * BK];   // 2 buf x {A,B} x 32KB = 128KB

  const int tid = threadIdx.x;
  const int lane = tid & 63;
  const int wid = tid >> 6;
  const int wr2 = wid >> 2;            // 0/1 : row half (A rows 128*wr2..)
  const int wc4 = wid & 3;             // 0..3: col quarter (B rows 64*wc4..)
  const int l15 = lane & 15;
  const int l4  = lane >> 4;

  // staging: 8 threads/row, row = i*64 + (tid>>3), src slot pre-swizzled
  const int srow = tid >> 3;                         // 0..63
  const int sslot = ((tid & 7) ^ (srow & 7)) * 8;    // element offset in row
  const int dstoff = wid * 512;                      // wave-uniform, +i*4096

  const size_t ebase = (size_t)e * S_TOK;
  const ushort_t* aS[4];
  const ushort_t* bS[4];
  const ushort_t* Bebase = B + (size_t)e * NDIM * KDIM;
#pragma unroll
  for (int i = 0; i < 4; ++i) {
    const int ra = m0 + i * 64 + srow;
    const int tok = (ra < cnt) ? tok_list[ebase + ra] : 0;
    aS[i] = A + (size_t)tok * KDIM + sslot;
    bS[i] = Bebase + (size_t)(n0 + i * 64 + srow) * KDIM + sslot;
  }

  // ds-read element offsets (swizzled), per fragment and K-half
  int oA[8][2], oB[4][2];
#pragma unroll
  for (int m = 0; m < 8; ++m) {
    const int rr = wr2 * 128 + m * 16 + l15;
#pragma unroll
    for (int kk = 0; kk < 2; ++kk)
      oA[m][kk] = rr * BK + (((kk * 4 + l4) ^ (rr & 7)) * 8);
  }
#pragma unroll
  for (int n = 0; n < 4; ++n) {
    const int rr = wc4 * 64 + n * 16 + l15;
#pragma unroll
    for (int kk = 0; kk < 2; ++kk)
      oB[n][kk] = rr * BK + (((kk * 4 + l4) ^ (rr & 7)) * 8);
  }

  f32x4 acc[8][4];
#pragma unroll
  for (int i = 0; i < 8; ++i)
#pragma unroll
    for (int j = 0; j < 4; ++j)
      acc[i][j] = (f32x4){0.f, 0.f, 0.f, 0.f};

  // prologue: stage tile 0 -> buf0, tile 1 -> buf1 (16 loads outstanding)
#pragma unroll
  for (int i = 0; i < 4; ++i) {
    load_lds16(aS[i], &Lds[0][0][i * 4096 + dstoff]);
    load_lds16(bS[i], &Lds[0][1][i * 4096 + dstoff]);
  }
  {
    const int k1 = (NK > 1) ? BK : 0;
#pragma unroll
    for (int i = 0; i < 4; ++i) {
      load_lds16(aS[i] + k1, &Lds[1][0][i * 4096 + dstoff]);
      load_lds16(bS[i] + k1, &Lds[1][1][i * 4096 + dstoff]);
    }
  }

  for (int t = 0; t < NK; ++t) {
    const int cb = t & 1;
    // wait: tile t landed (8 oldest of 16 outstanding), tile t+1 stays in flight
    asm volatile("s_waitcnt vmcnt(8)" ::: "memory");
    __builtin_amdgcn_s_barrier();
    __builtin_amdgcn_sched_barrier(0);

#pragma unroll
    for (int kk = 0; kk < 2; ++kk) {
      bf16x8 a[8], b[4];
#pragma unroll
      for (int m = 0; m < 8; ++m) a[m] = *(const bf16x8*)&Lds[cb][0][oA[m][kk]];
#pragma unroll
      for (int n = 0; n < 4; ++n) b[n] = *(const bf16x8*)&Lds[cb][1][oB[n][kk]];
#pragma unroll
      for (int m = 0; m < 8; ++m)
#pragma unroll
        for (int n = 0; n < 4; ++n)
          acc[m][n] = __builtin_amdgcn_mfma_f32_16x16x32_bf16(a[m], b[n], acc[m][n], 0, 0, 0);
    }

    __builtin_amdgcn_sched_barrier(0);
    __builtin_amdgcn_s_barrier();

    // issue tile t+2 into buf(t&1); clamp near tail (dummy re-reads tile NK-1,
    // lands in a buffer that is never read again -> keeps outstanding at 16)
    const int k2 = ((t + 2 < NK) ? (t + 2) : (NK - 1)) * BK;
#pragma unroll
    for (int i = 0; i < 4; ++i) {
      load_lds16(aS[i] + k2, &Lds[cb][0][i * 4096 + dstoff]);
      load_lds16(bS[i] + k2, &Lds[cb][1][i * 4096 + dstoff]);
    }
  }

  // epilogue
  const float* be = bias + (size_t)e * NDIM;
#pragma unroll
  for (int m = 0; m < 8; ++m) {
#pragma unroll
    for (int rr = 0; rr < 4; ++rr) {
      const int slot = m0 + wr2 * 128 + m * 16 + l4 * 4 + rr;
      if (slot >= cnt) continue;
      const int tok = tok_list[ebase + slot];
      if (EPI == 0) {
        ushort_t* hrow = Hout + (size_t)tok * NDIM;
#pragma unroll
        for (int n = 0; n < 4; ++n) {
          const int col = n0 + wc4 * 64 + n * 16 + l15;
          float v = acc[m][n][rr] + be[col];
          v = 0.5f * v * (1.0f + erff(v * 0.70710678118654752f));
          hrow[col] = f32_bf16(v);
        }
      } else {
        const float p = prob[tok];
        float* orow = out + (size_t)tok * NDIM;
#pragma unroll
        for (int n = 0; n < 4; ++n) {
          const int col = n0 + wc4 * 64 + n * 16 + l15;
          orow[col] = (acc[m][n][rr] + be[col]) * p;
        }
      }
    }
  }
}

extern "C" void kernel_launch(void* const* d_in, const int* in_sizes, int n_in,
                              void* d_out, int out_size, void* d_ws, size_t ws_size,
                              hipStream_t stream) {
  const float* x  = (const float*)d_in[0];
  const float* Wg = (const float*)d_in[1];
  const float* W1 = (const float*)d_in[2];
  const float* b1 = (const float*)d_in[3];
  const float* W2 = (const float*)d_in[4];
  const float* b2 = (const float*)d_in[5];
  float* out = (float*)d_out;

  const size_t MB = 1ull << 20;
  char* ws = (char*)d_ws;
  int* counts      = (int*)(ws);                 // 32 B
  int* plan        = (int*)(ws + 4096);          // ~600 B
  float* prob      = (float*)(ws + 64 * 1024);   // 64 KB
  int* tok_list    = (int*)(ws + 128 * 1024);    // 512 KB
  ushort_t* xbf    = (ushort_t*)(ws + 1 * MB);   // 32 MB
  ushort_t* W1bf   = (ushort_t*)(ws + 33 * MB);  // 64 MB
  ushort_t* W2bf   = (ushort_t*)(ws + 97 * MB);  // 64 MB
  ushort_t* H      = (ushort_t*)(ws + 161 * MB); // 128 MB

  zero_counts_kernel<<<1, 64, 0, stream>>>(counts);
  gate_kernel<<<S_TOK / 4, 256, 0, stream>>>(x, Wg, xbf, prob, counts, tok_list);
  plan_kernel<<<1, 64, 0, stream>>>(counts, plan);

  cast2_kernel<<<32768, 256, 0, stream>>>(W1, W1bf, W2, W2bf);

  ffn_kernel<D_DIM, F_DIM, 0><<<(F_DIM / BN) * MT_MAX, 512, 0, stream>>>(
      xbf, W1bf, b1, nullptr, counts, tok_list, plan, H, nullptr);

  ffn_kernel<F_DIM, D_DIM, 1><<<(D_DIM / BN) * MT_MAX, 512, 0, stream>>>(
      H, W2bf, b2, prob, counts, tok_list, plan, nullptr, out);
}

// Round 7
// 761.223 us; speedup vs baseline: 1.1531x; 1.1531x over previous
//
#include <hip/hip_runtime.h>

#define S_TOK 16384   // S*N tokens
#define D_DIM 1024
#define F_DIM 4096
#define E_NUM 8

#define BM 128
#define BN 128
#define BK 32
#define MT_MAX 136    // sum_e ceil(cnt_e/128) <= 128 + 8 = 136

typedef short bf16x8 __attribute__((ext_vector_type(8)));
typedef float f32x4 __attribute__((ext_vector_type(4)));
typedef unsigned short ushort_t;

static __device__ __forceinline__ unsigned short f32_bf16(float f) {
  unsigned u = __float_as_uint(f);
  return (unsigned short)((u + 0x7FFFu + ((u >> 16) & 1u)) >> 16);
}

static __device__ __forceinline__ unsigned int pack_bf16x2(float a, float b) {
  unsigned ua = __float_as_uint(a);
  unsigned ub = __float_as_uint(b);
  unsigned lo = (ua + 0x7FFFu + ((ua >> 16) & 1u)) >> 16;
  unsigned hi = (ub + 0x7FFFu + ((ub >> 16) & 1u)) & 0xFFFF0000u;
  return lo | hi;
}

static __device__ __forceinline__ uint2 cvt_f4_bf4(const float4 v) {
  uint2 r;
  r.x = pack_bf16x2(v.x, v.y);
  r.y = pack_bf16x2(v.z, v.w);
  return r;
}

static __device__ __forceinline__ void load_lds16(const void* g, void* l) {
  __builtin_amdgcn_global_load_lds(g, l, 16, 0, 0);
}

// ---------------- zero counts ----------------
__global__ void zero_counts_kernel(int* counts) {
  if (threadIdx.x < E_NUM) counts[threadIdx.x] = 0;
}

// ---------------- fp32 -> bf16 cast of W1 and W2 in one launch ----------------
__global__ void cast2_kernel(const float* __restrict__ w1, ushort_t* __restrict__ o1,
                             const float* __restrict__ w2, ushort_t* __restrict__ o2) {
  const int half = 16384;
  const float* src = (blockIdx.x < half) ? w1 : w2;
  ushort_t* dst = (blockIdx.x < half) ? o1 : o2;
  const int b = (blockIdx.x < half) ? blockIdx.x : (blockIdx.x - half);
  const size_t base = ((size_t)b * blockDim.x + threadIdx.x) * 8;
  const float4 v0 = *(const float4*)(src + base);
  const float4 v1 = *(const float4*)(src + base + 4);
  const uint2 a = cvt_f4_bf4(v0), c = cvt_f4_bf4(v1);
  uint4 w; w.x = a.x; w.y = a.y; w.z = c.x; w.w = c.y;
  *(uint4*)(dst + base) = w;
}

// ---------------- gating (+ x cast to bf16) ----------------
__global__ void gate_kernel(const float* __restrict__ x,
                            const float* __restrict__ Wg,
                            ushort_t* __restrict__ xbf,
                            float* __restrict__ prob,
                            int* __restrict__ counts,
                            int* __restrict__ tok_list) {
  const int wv = threadIdx.x >> 6;
  const int lane = threadIdx.x & 63;
  const int t = blockIdx.x * 4 + wv;
  const float* xr = x + (size_t)t * D_DIM;
  ushort_t* xb = xbf + (size_t)t * D_DIM;

  float acc[E_NUM];
#pragma unroll
  for (int e = 0; e < E_NUM; ++e) acc[e] = 0.0f;

#pragma unroll
  for (int i = 0; i < 4; ++i) {
    const int k = i * 256 + lane * 4;
    const float4 v = *(const float4*)(xr + k);
    *(uint2*)(xb + k) = cvt_f4_bf4(v);
#pragma unroll
    for (int e = 0; e < E_NUM; ++e) {
      const float4 w = *(const float4*)(Wg + e * D_DIM + k);
      acc[e] += v.x * w.x + v.y * w.y + v.z * w.z + v.w * w.w;
    }
  }
#pragma unroll
  for (int e = 0; e < E_NUM; ++e) {
#pragma unroll
    for (int off = 32; off > 0; off >>= 1)
      acc[e] += __shfl_xor(acc[e], off, 64);
  }
  if (lane == 0) {
    float m = acc[0]; int bi = 0;
#pragma unroll
    for (int e = 1; e < E_NUM; ++e) {
      if (acc[e] > m) { m = acc[e]; bi = e; }
    }
    float s = 0.0f;
#pragma unroll
    for (int e = 0; e < E_NUM; ++e) s += expf(acc[e] - m);
    prob[t] = 1.0f / s;             // softmax prob of the argmax logit
    int p = atomicAdd(&counts[bi], 1);
    tok_list[bi * S_TOK + p] = t;
  }
}

// ---------------- tile plan: dense (expert, m0) table, BM=128 ----------------
__global__ void plan_kernel(const int* __restrict__ counts, int* __restrict__ plan) {
  if (threadIdx.x == 0) {
    int t = 0;
    for (int e = 0; e < E_NUM; ++e) {
      const int nt = (counts[e] + BM - 1) / BM;
      for (int i = 0; i < nt; ++i) {
        plan[1 + t] = e;
        plan[1 + MT_MAX + t] = i * BM;
        ++t;
      }
    }
    plan[0] = t;
  }
}

// ---------------- grouped GEMM: 128^2, BK=32, dbuf, XOR-swizzled LDS ----------
// R3 structure (best measured) + T2 swizzle. Row = 64B = 4 x 16B slots;
// phys_slot = log_slot ^ ((row>>1)&3): rows at the same slot now spread over
// 8 bank-groups -> 2 lanes/bank on ds_read_b128 (free, m136).
// Applied to the global SOURCE at stage time (LDS dest linear, rule #21) and
// to the ds_read addresses (both-sides, same involution).
template <int KDIM, int NDIM, int EPI>
__launch_bounds__(256, 4)
__global__ void ffn_kernel(const ushort_t* __restrict__ A,
                           const ushort_t* __restrict__ B,
                           const float* __restrict__ bias,
                           const float* __restrict__ prob,
                           const int* __restrict__ counts,
                           const int* __restrict__ tok_list,
                           const int* __restrict__ plan,
                           ushort_t* __restrict__ Hout,
                           float* __restrict__ out) {
  constexpr int NT = NDIM / BN;
  constexpr int NK = KDIM / BK;
  const int ntiles = plan[0];
  const int live = ntiles * NT;
  if (blockIdx.x >= live) return;
  // runtime-bijective XCD swizzle over the LIVE range (m204 formula)
  const int q = live >> 3, r = live & 7;
  const int xcd = blockIdx.x & 7, idx = blockIdx.x >> 3;
  const int wg = (xcd < r ? xcd * (q + 1) : r * (q + 1) + (xcd - r) * q) + idx;
  const int tile = wg / NT;            // m slow, n fast: A-panel hot per XCD
  const int n0 = (wg % NT) * BN;
  const int e = plan[1 + tile];
  const int m0 = plan[1 + MT_MAX + tile];
  const int cnt = counts[e];

  __shared__ ushort_t As[2][BM * BK];   // 2 x 8 KB
  __shared__ ushort_t Bs[2][BM * BK];   // 2 x 8 KB

  const int tid = threadIdx.x;
  const int lane = tid & 63;
  const int w = tid >> 6;
  const int wr = (w >> 1) * 64;
  const int wc = (w & 1) * 64;
  const int l15 = lane & 15;
  const int l4  = lane >> 4;

  // staging: 4 threads/row, 64 rows per instr; source slot pre-swizzled
  const int srow = tid >> 2;                              // 0..63
  const int sslot = ((tid & 3) ^ ((srow >> 1) & 3)) * 8;  // element offset
  const int dstoff = w * 512;                             // wave-uniform base

  const size_t ebase = (size_t)e * S_TOK;
  const int tokA0 = (m0 + srow < cnt) ? tok_list[ebase + m0 + srow] : 0;
  const int tokA1 = (m0 + 64 + srow < cnt) ? tok_list[ebase + m0 + 64 + srow] : 0;
  const ushort_t* pA0 = A + (size_t)tokA0 * KDIM + sslot;
  const ushort_t* pA1 = A + (size_t)tokA1 * KDIM + sslot;
  const ushort_t* Be = B + (size_t)e * NDIM * KDIM;
  const ushort_t* pB0 = Be + (size_t)(n0 + srow) * KDIM + sslot;
  const ushort_t* pB1 = Be + (size_t)(n0 + 64 + srow) * KDIM + sslot;

  // ds-read element offsets (swizzled)
  int oA[4], oB[4];
#pragma unroll
  for (int m = 0; m < 4; ++m) {
    const int rr = wr + m * 16 + l15;
    oA[m] = rr * BK + ((l4 ^ ((rr >> 1) & 3)) * 8);
  }
#pragma unroll
  for (int n = 0; n < 4; ++n) {
    const int rr = wc + n * 16 + l15;
    oB[n] = rr * BK + ((l4 ^ ((rr >> 1) & 3)) * 8);
  }

  f32x4 acc[4][4];
#pragma unroll
  for (int i = 0; i < 4; ++i)
#pragma unroll
    for (int j = 0; j < 4; ++j)
      acc[i][j] = (f32x4){0.f, 0.f, 0.f, 0.f};

  // prologue: stage tile 0 into buf 0
  load_lds16(pA0, &As[0][dstoff]);
  load_lds16(pA1, &As[0][2048 + dstoff]);
  load_lds16(pB0, &Bs[0][dstoff]);
  load_lds16(pB1, &Bs[0][2048 + dstoff]);
  __syncthreads();

  int cb = 0;
  for (int t = 0; t < NK; ++t) {
    if (t + 1 < NK) {
      const int k0 = (t + 1) * BK;
      const int nb = cb ^ 1;
      load_lds16(pA0 + k0, &As[nb][dstoff]);
      load_lds16(pA1 + k0, &As[nb][2048 + dstoff]);
      load_lds16(pB0 + k0, &Bs[nb][dstoff]);
      load_lds16(pB1 + k0, &Bs[nb][2048 + dstoff]);
    }

    bf16x8 a[4], b[4];
#pragma unroll
    for (int i = 0; i < 4; ++i) {
      a[i] = *(const bf16x8*)&As[cb][oA[i]];
      b[i] = *(const bf16x8*)&Bs[cb][oB[i]];
    }
#pragma unroll
    for (int mi = 0; mi < 4; ++mi)
#pragma unroll
      for (int ni = 0; ni < 4; ++ni)
        acc[mi][ni] = __builtin_amdgcn_mfma_f32_16x16x32_bf16(a[mi], b[ni], acc[mi][ni], 0, 0, 0);

    __syncthreads();   // drains vmcnt/lgkm: next buffer staged & safe
    cb ^= 1;
  }

  // epilogue
  const float* be = bias + (size_t)e * NDIM;
#pragma unroll
  for (int mi = 0; mi < 4; ++mi) {
#pragma unroll
    for (int rr = 0; rr < 4; ++rr) {
      const int slot = m0 + wr + mi * 16 + l4 * 4 + rr;
      if (slot >= cnt) continue;
      const int tok = tok_list[ebase + slot];
      if (EPI == 0) {
        ushort_t* hrow = Hout + (size_t)tok * NDIM;
#pragma unroll
        for (int ni = 0; ni < 4; ++ni) {
          const int col = n0 + wc + ni * 16 + l15;
          float v = acc[mi][ni][rr] + be[col];
          v = 0.5f * v * (1.0f + erff(v * 0.70710678118654752f));
          hrow[col] = f32_bf16(v);
        }
      } else {
        const float p = prob[tok];
        float* orow = out + (size_t)tok * NDIM;
#pragma unroll
        for (int ni = 0; ni < 4; ++ni) {
          const int col = n0 + wc + ni * 16 + l15;
          orow[col] = (acc[mi][ni][rr] + be[col]) * p;
        }
      }
    }
  }
}

extern "C" void kernel_launch(void* const* d_in, const int* in_sizes, int n_in,
                              void* d_out, int out_size, void* d_ws, size_t ws_size,
                              hipStream_t stream) {
  const float* x  = (const float*)d_in[0];
  const float* Wg = (const float*)d_in[1];
  const float* W1 = (const float*)d_in[2];
  const float* b1 = (const float*)d_in[3];
  const float* W2 = (const float*)d_in[4];
  const float* b2 = (const float*)d_in[5];
  float* out = (float*)d_out;

  const size_t MB = 1ull << 20;
  char* ws = (char*)d_ws;
  int* counts      = (int*)(ws);                 // 32 B
  int* plan        = (int*)(ws + 4096);          // ~1.1 KB
  float* prob      = (float*)(ws + 64 * 1024);   // 64 KB
  int* tok_list    = (int*)(ws + 128 * 1024);    // 512 KB
  ushort_t* xbf    = (ushort_t*)(ws + 1 * MB);   // 32 MB
  ushort_t* W1bf   = (ushort_t*)(ws + 33 * MB);  // 64 MB
  ushort_t* W2bf   = (ushort_t*)(ws + 97 * MB);  // 64 MB
  ushort_t* H      = (ushort_t*)(ws + 161 * MB); // 128 MB

  zero_counts_kernel<<<1, 64, 0, stream>>>(counts);
  gate_kernel<<<S_TOK / 4, 256, 0, stream>>>(x, Wg, xbf, prob, counts, tok_list);
  plan_kernel<<<1, 64, 0, stream>>>(counts, plan);

  cast2_kernel<<<32768, 256, 0, stream>>>(W1, W1bf, W2, W2bf);

  ffn_kernel<D_DIM, F_DIM, 0><<<(F_DIM / BN) * MT_MAX, 256, 0, stream>>>(
      xbf, W1bf, b1, nullptr, counts, tok_list, plan, H, nullptr);

  ffn_kernel<F_DIM, D_DIM, 1><<<(D_DIM / BN) * MT_MAX, 256, 0, stream>>>(
      H, W2bf, b2, prob, counts, tok_list, plan, nullptr, out);
}

// Round 8
// 709.345 us; speedup vs baseline: 1.2374x; 1.0731x over previous
//
#include <hip/hip_runtime.h>

#define S_TOK 16384   // S*N tokens
#define D_DIM 1024
#define F_DIM 4096
#define E_NUM 8

#define BM 128
#define BN 128
#define BK 64
#define MT_MAX 136    // sum_e ceil(cnt_e/128) <= 128 + 8 = 136

typedef short bf16x8 __attribute__((ext_vector_type(8)));
typedef float f32x4 __attribute__((ext_vector_type(4)));
typedef unsigned short ushort_t;

static __device__ __forceinline__ unsigned short f32_bf16(float f) {
  unsigned u = __float_as_uint(f);
  return (unsigned short)((u + 0x7FFFu + ((u >> 16) & 1u)) >> 16);
}

static __device__ __forceinline__ unsigned int pack_bf16x2(float a, float b) {
  unsigned ua = __float_as_uint(a);
  unsigned ub = __float_as_uint(b);
  unsigned lo = (ua + 0x7FFFu + ((ua >> 16) & 1u)) >> 16;
  unsigned hi = (ub + 0x7FFFu + ((ub >> 16) & 1u)) & 0xFFFF0000u;
  return lo | hi;
}

static __device__ __forceinline__ uint2 cvt_f4_bf4(const float4 v) {
  uint2 r;
  r.x = pack_bf16x2(v.x, v.y);
  r.y = pack_bf16x2(v.z, v.w);
  return r;
}

static __device__ __forceinline__ void load_lds16(const void* g, void* l) {
  __builtin_amdgcn_global_load_lds(g, l, 16, 0, 0);
}

// ---------------- zero counts ----------------
__global__ void zero_counts_kernel(int* counts) {
  if (threadIdx.x < E_NUM) counts[threadIdx.x] = 0;
}

// ---------------- fp32 -> bf16 cast of W1 and W2 in one launch ----------------
__global__ void cast2_kernel(const float* __restrict__ w1, ushort_t* __restrict__ o1,
                             const float* __restrict__ w2, ushort_t* __restrict__ o2) {
  const int half = 16384;
  const float* src = (blockIdx.x < half) ? w1 : w2;
  ushort_t* dst = (blockIdx.x < half) ? o1 : o2;
  const int b = (blockIdx.x < half) ? blockIdx.x : (blockIdx.x - half);
  const size_t base = ((size_t)b * blockDim.x + threadIdx.x) * 8;
  const float4 v0 = *(const float4*)(src + base);
  const float4 v1 = *(const float4*)(src + base + 4);
  const uint2 a = cvt_f4_bf4(v0), c = cvt_f4_bf4(v1);
  uint4 w; w.x = a.x; w.y = a.y; w.z = c.x; w.w = c.y;
  *(uint4*)(dst + base) = w;
}

// ---------------- gating (+ x cast to bf16) ----------------
__global__ void gate_kernel(const float* __restrict__ x,
                            const float* __restrict__ Wg,
                            ushort_t* __restrict__ xbf,
                            float* __restrict__ prob,
                            int* __restrict__ counts,
                            int* __restrict__ tok_list) {
  const int wv = threadIdx.x >> 6;
  const int lane = threadIdx.x & 63;
  const int t = blockIdx.x * 4 + wv;
  const float* xr = x + (size_t)t * D_DIM;
  ushort_t* xb = xbf + (size_t)t * D_DIM;

  float acc[E_NUM];
#pragma unroll
  for (int e = 0; e < E_NUM; ++e) acc[e] = 0.0f;

#pragma unroll
  for (int i = 0; i < 4; ++i) {
    const int k = i * 256 + lane * 4;
    const float4 v = *(const float4*)(xr + k);
    *(uint2*)(xb + k) = cvt_f4_bf4(v);
#pragma unroll
    for (int e = 0; e < E_NUM; ++e) {
      const float4 w = *(const float4*)(Wg + e * D_DIM + k);
      acc[e] += v.x * w.x + v.y * w.y + v.z * w.z + v.w * w.w;
    }
  }
#pragma unroll
  for (int e = 0; e < E_NUM; ++e) {
#pragma unroll
    for (int off = 32; off > 0; off >>= 1)
      acc[e] += __shfl_xor(acc[e], off, 64);
  }
  if (lane == 0) {
    float m = acc[0]; int bi = 0;
#pragma unroll
    for (int e = 1; e < E_NUM; ++e) {
      if (acc[e] > m) { m = acc[e]; bi = e; }
    }
    float s = 0.0f;
#pragma unroll
    for (int e = 0; e < E_NUM; ++e) s += expf(acc[e] - m);
    prob[t] = 1.0f / s;             // softmax prob of the argmax logit
    int p = atomicAdd(&counts[bi], 1);
    tok_list[bi * S_TOK + p] = t;
  }
}

// ---------------- tile plan: dense (expert, m0) table, BM=128 ----------------
__global__ void plan_kernel(const int* __restrict__ counts, int* __restrict__ plan) {
  if (threadIdx.x == 0) {
    int t = 0;
    for (int e = 0; e < E_NUM; ++e) {
      const int nt = (counts[e] + BM - 1) / BM;
      for (int i = 0; i < nt; ++i) {
        plan[1 + t] = e;
        plan[1 + MT_MAX + t] = i * BM;
        ++t;
      }
    }
    plan[0] = t;
  }
}

// ---------------- grouped GEMM: 128^2, BK=64, SINGLE buffer (m97-exact) ------
// 32 MFMA per wave between barrier pairs (2x R7's amortization); 32 KB LDS ->
// ~5 blocks/CU co-residency provides stage/compute overlap (m114).
// Swizzle (T2, both-sides): row = 128B = 8 x 16B slots; phys = log ^ (row&7).
// Applied to the global SOURCE (LDS dest linear, rule #21) and ds_read addrs.
template <int KDIM, int NDIM, int EPI>
__launch_bounds__(256, 4)
__global__ void ffn_kernel(const ushort_t* __restrict__ A,
                           const ushort_t* __restrict__ B,
                           const float* __restrict__ bias,
                           const float* __restrict__ prob,
                           const int* __restrict__ counts,
                           const int* __restrict__ tok_list,
                           const int* __restrict__ plan,
                           ushort_t* __restrict__ Hout,
                           float* __restrict__ out) {
  constexpr int NT = NDIM / BN;
  constexpr int NK = KDIM / BK;
  const int ntiles = plan[0];
  const int live = ntiles * NT;
  if (blockIdx.x >= live) return;
  // runtime-bijective XCD swizzle over the LIVE range (m204 formula)
  const int q = live >> 3, r = live & 7;
  const int xcd = blockIdx.x & 7, idx = blockIdx.x >> 3;
  const int wg = (xcd < r ? xcd * (q + 1) : r * (q + 1) + (xcd - r) * q) + idx;
  const int tile = wg / NT;            // m slow, n fast: A-panel hot per XCD
  const int n0 = (wg % NT) * BN;
  const int e = plan[1 + tile];
  const int m0 = plan[1 + MT_MAX + tile];
  const int cnt = counts[e];

  __shared__ ushort_t As[BM * BK];   // 16 KB
  __shared__ ushort_t Bs[BM * BK];   // 16 KB

  const int tid = threadIdx.x;
  const int lane = tid & 63;
  const int w = tid >> 6;
  const int wr = (w >> 1) * 64;
  const int wc = (w & 1) * 64;
  const int l15 = lane & 15;
  const int l4  = lane >> 4;

  // staging: wave w covers rows [w*32, w*32+32); instr j covers 8 rows.
  // lane l -> row w*32 + j*8 + (l>>3), 16B slot (l&7); source pre-swizzled:
  // logical slot = (l&7) ^ (row&7) = (l&7) ^ (l>>3)   (j*8 drops out mod 8)
  const int sub = lane >> 3;                       // 0..7
  const int sslot = ((lane & 7) ^ sub) * 8;        // element offset in row
  const int dstoff = w * 2048;                     // wave base (elements)

  const size_t ebase = (size_t)e * S_TOK;
  const ushort_t* Be = B + (size_t)e * NDIM * KDIM;
  const ushort_t* pA[4];
  const ushort_t* pB[4];
#pragma unroll
  for (int j = 0; j < 4; ++j) {
    const int ra = m0 + w * 32 + j * 8 + sub;
    const int tok = (ra < cnt) ? tok_list[ebase + ra] : 0;
    pA[j] = A + (size_t)tok * KDIM + sslot;
    pB[j] = Be + (size_t)(n0 + w * 32 + j * 8 + sub) * KDIM + sslot;
  }

  // ds-read element offsets (swizzled), per fragment and K-half
  int oA[4][2], oB[4][2];
#pragma unroll
  for (int m = 0; m < 4; ++m) {
    const int rr = wr + m * 16 + l15;
#pragma unroll
    for (int kk = 0; kk < 2; ++kk)
      oA[m][kk] = rr * BK + (((kk * 4 + l4) ^ (rr & 7)) * 8);
  }
#pragma unroll
  for (int n = 0; n < 4; ++n) {
    const int rr = wc + n * 16 + l15;
#pragma unroll
    for (int kk = 0; kk < 2; ++kk)
      oB[n][kk] = rr * BK + (((kk * 4 + l4) ^ (rr & 7)) * 8);
  }

  f32x4 acc[4][4];
#pragma unroll
  for (int i = 0; i < 4; ++i)
#pragma unroll
    for (int j = 0; j < 4; ++j)
      acc[i][j] = (f32x4){0.f, 0.f, 0.f, 0.f};

  for (int t = 0; t < NK; ++t) {
    const int k0 = t * BK;
#pragma unroll
    for (int j = 0; j < 4; ++j) {
      load_lds16(pA[j] + k0, &As[dstoff + j * 512]);
      load_lds16(pB[j] + k0, &Bs[dstoff + j * 512]);
    }
    __syncthreads();   // drains vmcnt(0): tile staged

#pragma unroll
    for (int kk = 0; kk < 2; ++kk) {
      bf16x8 a[4], b[4];
#pragma unroll
      for (int i = 0; i < 4; ++i) {
        a[i] = *(const bf16x8*)&As[oA[i][kk]];
        b[i] = *(const bf16x8*)&Bs[oB[i][kk]];
      }
#pragma unroll
      for (int mi = 0; mi < 4; ++mi)
#pragma unroll
        for (int ni = 0; ni < 4; ++ni)
          acc[mi][ni] = __builtin_amdgcn_mfma_f32_16x16x32_bf16(a[mi], b[ni], acc[mi][ni], 0, 0, 0);
    }

    __syncthreads();   // compute done: buffer may be overwritten
  }

  // epilogue
  const float* be = bias + (size_t)e * NDIM;
#pragma unroll
  for (int mi = 0; mi < 4; ++mi) {
#pragma unroll
    for (int rr = 0; rr < 4; ++rr) {
      const int slot = m0 + wr + mi * 16 + l4 * 4 + rr;
      if (slot >= cnt) continue;
      const int tok = tok_list[ebase + slot];
      if (EPI == 0) {
        ushort_t* hrow = Hout + (size_t)tok * NDIM;
#pragma unroll
        for (int ni = 0; ni < 4; ++ni) {
          const int col = n0 + wc + ni * 16 + l15;
          float v = acc[mi][ni][rr] + be[col];
          v = 0.5f * v * (1.0f + erff(v * 0.70710678118654752f));
          hrow[col] = f32_bf16(v);
        }
      } else {
        const float p = prob[tok];
        float* orow = out + (size_t)tok * NDIM;
#pragma unroll
        for (int ni = 0; ni < 4; ++ni) {
          const int col = n0 + wc + ni * 16 + l15;
          orow[col] = (acc[mi][ni][rr] + be[col]) * p;
        }
      }
    }
  }
}

extern "C" void kernel_launch(void* const* d_in, const int* in_sizes, int n_in,
                              void* d_out, int out_size, void* d_ws, size_t ws_size,
                              hipStream_t stream) {
  const float* x  = (const float*)d_in[0];
  const float* Wg = (const float*)d_in[1];
  const float* W1 = (const float*)d_in[2];
  const float* b1 = (const float*)d_in[3];
  const float* W2 = (const float*)d_in[4];
  const float* b2 = (const float*)d_in[5];
  float* out = (float*)d_out;

  const size_t MB = 1ull << 20;
  char* ws = (char*)d_ws;
  int* counts      = (int*)(ws);                 // 32 B
  int* plan        = (int*)(ws + 4096);          // ~1.1 KB
  float* prob      = (float*)(ws + 64 * 1024);   // 64 KB
  int* tok_list    = (int*)(ws + 128 * 1024);    // 512 KB
  ushort_t* xbf    = (ushort_t*)(ws + 1 * MB);   // 32 MB
  ushort_t* W1bf   = (ushort_t*)(ws + 33 * MB);  // 64 MB
  ushort_t* W2bf   = (ushort_t*)(ws + 97 * MB);  // 64 MB
  ushort_t* H      = (ushort_t*)(ws + 161 * MB); // 128 MB

  zero_counts_kernel<<<1, 64, 0, stream>>>(counts);
  gate_kernel<<<S_TOK / 4, 256, 0, stream>>>(x, Wg, xbf, prob, counts, tok_list);
  plan_kernel<<<1, 64, 0, stream>>>(counts, plan);

  cast2_kernel<<<32768, 256, 0, stream>>>(W1, W1bf, W2, W2bf);

  ffn_kernel<D_DIM, F_DIM, 0><<<(F_DIM / BN) * MT_MAX, 256, 0, stream>>>(
      xbf, W1bf, b1, nullptr, counts, tok_list, plan, H, nullptr);

  ffn_kernel<F_DIM, D_DIM, 1><<<(D_DIM / BN) * MT_MAX, 256, 0, stream>>>(
      H, W2bf, b2, prob, counts, tok_list, plan, nullptr, out);
}